// Round 1
// baseline (1522.025 us; speedup 1.0000x reference)
//
#include <hip/hip_runtime.h>
#include <math.h>

#define NN 10000
#define NE 320000
#define NODE_F 64
#define EDGE_F 32
#define HDIM 256
#define HEADS 8
#define LAYERS 6
#define NG 16

// ---------------------------------------------------------------- CSR build
__global__ void count_kernel(const int* __restrict__ dst, int* __restrict__ cnt) {
    int e = blockIdx.x * 256 + threadIdx.x;
    if (e < NE) atomicAdd(&cnt[dst[e]], 1);
}

__global__ void scan_kernel(const int* __restrict__ cnt, int* __restrict__ row_ptr,
                            int* __restrict__ pos) {
    __shared__ int part[1024];
    int t = threadIdx.x;
    const int chunk = (NN + 1023) / 1024;  // 10
    int lo = t * chunk, hi = min(NN, lo + chunk);
    int s = 0;
    for (int i = lo; i < hi; ++i) s += cnt[i];
    part[t] = s;
    __syncthreads();
    for (int off = 1; off < 1024; off <<= 1) {
        int v = (t >= off) ? part[t - off] : 0;
        __syncthreads();
        part[t] += v;
        __syncthreads();
    }
    int base = (t == 0) ? 0 : part[t - 1];
    for (int i = lo; i < hi; ++i) {
        row_ptr[i] = base;
        pos[i] = base;
        base += cnt[i];
    }
    if (t == 1023) row_ptr[NN] = part[1023];
}

__global__ void scatter_kernel(const int* __restrict__ src, const int* __restrict__ dst,
                               int* __restrict__ pos, int* __restrict__ csr_src,
                               int* __restrict__ csr_eid) {
    int e = blockIdx.x * 256 + threadIdx.x;
    if (e >= NE) return;
    int d = dst[e];
    int idx = atomicAdd(&pos[d], 1);
    csr_src[idx] = src[e];
    csr_eid[idx] = e;
}

// mean of incoming raw edge_attr per node (PyG fill_value='mean' precursor)
__global__ __launch_bounds__(64) void mean_attr_kernel(const float* __restrict__ edge_attr,
                                                       const int* __restrict__ row_ptr,
                                                       const int* __restrict__ csr_eid,
                                                       float* __restrict__ mean_attr) {
    int n = blockIdx.x, l = threadIdx.x;
    if (l >= EDGE_F) return;
    int start = row_ptr[n], end = row_ptr[n + 1];
    float s = 0.f;
    for (int idx = start; idx < end; ++idx) s += edge_attr[(size_t)csr_eid[idx] * EDGE_F + l];
    int c = end - start;
    mean_attr[n * EDGE_F + l] = c > 0 ? s / (float)c : 0.f;
}

// ---------------------------------------------------------------- edge-attn weight folding
// v[i,h,k] = sum_o att_edge[i,h,o] * lin_edge_w[i, h*32+o, k]
__global__ void v_kernel(const float* __restrict__ att_edge, const float* __restrict__ lin_edge_w,
                         float* __restrict__ v) {
    int idx = blockIdx.x * 256 + threadIdx.x;
    if (idx >= LAYERS * HEADS * HDIM) return;
    int i = idx / (HEADS * HDIM);
    int r = idx % (HEADS * HDIM);
    int h = r / HDIM, k = r % HDIM;
    float s = 0.f;
    #pragma unroll 4
    for (int o = 0; o < 32; ++o)
        s += att_edge[(i * HEADS + h) * 32 + o] *
             lin_edge_w[((size_t)i * HDIM + h * 32 + o) * HDIM + k];
    v[idx] = s;
}

// we[i,h,f] = sum_k v[i,h,k]*edge_emb_w[k,f];  be[i,h] = sum_k v[i,h,k]*edge_emb_b[k]
__global__ void we_kernel(const float* __restrict__ v, const float* __restrict__ edge_emb_w,
                          const float* __restrict__ edge_emb_b, float* __restrict__ we,
                          float* __restrict__ be) {
    int idx = blockIdx.x * 256 + threadIdx.x;
    if (idx < LAYERS * HEADS * EDGE_F) {
        int i = idx / (HEADS * EDGE_F);
        int r = idx % (HEADS * EDGE_F);
        int h = r >> 5, f = r & 31;
        float s = 0.f;
        for (int k = 0; k < HDIM; ++k)
            s += v[(i * HEADS + h) * HDIM + k] * edge_emb_w[k * EDGE_F + f];
        we[idx] = s;
    } else if (idx < LAYERS * HEADS * EDGE_F + LAYERS * HEADS) {
        int j = idx - LAYERS * HEADS * EDGE_F;
        int i = j / HEADS, h = j % HEADS;
        float s = 0.f;
        for (int k = 0; k < HDIM; ++k) s += v[(i * HEADS + h) * HDIM + k] * edge_emb_b[k];
        be[j] = s;
    }
}

// ---------------------------------------------------------------- f32 tiled GEMM: C[n,j] = sum_k A[n,k]*B[j,k] (+bias[j])
__global__ __launch_bounds__(256) void gemm_bt(const float* __restrict__ A,
                                               const float* __restrict__ B,
                                               const float* __restrict__ bias,
                                               float* __restrict__ C, int N, int K, int J) {
    __shared__ float As[16][65];
    __shared__ float Bs[16][65];
    int nb = blockIdx.y * 64, jb = blockIdx.x * 64;
    int t = threadIdx.x;
    int tx = t & 15, ty = t >> 4;
    float acc[4][4] = {};
    int lrow = t >> 2, kq = (t & 3) * 4;
    for (int kt = 0; kt < K; kt += 16) {
        float4 av = make_float4(0.f, 0.f, 0.f, 0.f);
        if (nb + lrow < N) av = *(const float4*)(A + (size_t)(nb + lrow) * K + kt + kq);
        As[kq + 0][lrow] = av.x; As[kq + 1][lrow] = av.y;
        As[kq + 2][lrow] = av.z; As[kq + 3][lrow] = av.w;
        float4 bv = *(const float4*)(B + (size_t)(jb + lrow) * K + kt + kq);
        Bs[kq + 0][lrow] = bv.x; Bs[kq + 1][lrow] = bv.y;
        Bs[kq + 2][lrow] = bv.z; Bs[kq + 3][lrow] = bv.w;
        __syncthreads();
        #pragma unroll
        for (int k = 0; k < 16; ++k) {
            float a[4], b[4];
            #pragma unroll
            for (int i = 0; i < 4; ++i) a[i] = As[k][ty * 4 + i];
            #pragma unroll
            for (int j = 0; j < 4; ++j) b[j] = Bs[k][tx * 4 + j];
            #pragma unroll
            for (int i = 0; i < 4; ++i)
                #pragma unroll
                for (int j = 0; j < 4; ++j) acc[i][j] += a[i] * b[j];
        }
        __syncthreads();
    }
    #pragma unroll
    for (int i = 0; i < 4; ++i) {
        int n = nb + ty * 4 + i;
        if (n >= N) continue;
        #pragma unroll
        for (int j = 0; j < 4; ++j) {
            int jj = jb + tx * 4 + j;
            C[(size_t)n * J + jj] = acc[i][j] + (bias ? bias[jj] : 0.f);
        }
    }
}

// ---------------------------------------------------------------- per-node a_src/a_dst from xw
__global__ void asrcdst_kernel(const float* __restrict__ xw, const float* __restrict__ att_s,
                               const float* __restrict__ att_d, float* __restrict__ a_src,
                               float* __restrict__ a_dst) {
    int tid = blockIdx.x * 256 + threadIdx.x;
    if (tid >= NN * HEADS) return;
    int n = tid >> 3, h = tid & 7;
    const float4* xv = (const float4*)(xw + (size_t)n * HDIM + h * 32);
    const float4* sv = (const float4*)(att_s + h * 32);
    const float4* dv = (const float4*)(att_d + h * 32);
    float s1 = 0.f, s2 = 0.f;
    #pragma unroll
    for (int q = 0; q < 8; ++q) {
        float4 xx = xv[q], aa = sv[q], bb = dv[q];
        s1 += xx.x * aa.x + xx.y * aa.y + xx.z * aa.z + xx.w * aa.w;
        s2 += xx.x * bb.x + xx.y * bb.y + xx.z * bb.z + xx.w * bb.w;
    }
    a_src[tid] = s1;
    a_dst[tid] = s2;
}

// ---------------------------------------------------------------- per-edge alpha (leaky-relu'd logits)
__global__ __launch_bounds__(256) void edge_alpha_kernel(const int* __restrict__ src,
                                                         const int* __restrict__ dst,
                                                         const float* __restrict__ edge_attr,
                                                         const float* __restrict__ a_src,
                                                         const float* __restrict__ a_dst,
                                                         const float* __restrict__ we_i,
                                                         const float* __restrict__ be_i,
                                                         float* __restrict__ alpha) {
    int g = threadIdx.x >> 5, c = threadIdx.x & 31;
    int e = blockIdx.x * 8 + g;  // NE % 8 == 0
    float ea = edge_attr[(size_t)e * EDGE_F + c];
    float p[8];
    #pragma unroll
    for (int h = 0; h < 8; ++h) p[h] = ea * we_i[h * 32 + c];
    #pragma unroll
    for (int off = 16; off >= 1; off >>= 1)
        #pragma unroll
        for (int h = 0; h < 8; ++h) p[h] += __shfl_xor(p[h], off, 32);
    if (c < 8) {
        int h = c, s = src[e], d = dst[e];
        float al = a_src[s * 8 + h] + a_dst[d * 8 + h] + p[h] + be_i[h];
        alpha[(size_t)e * 8 + h] = al > 0.f ? al : 0.2f * al;
    }
}

// self-loop alpha per node
__global__ __launch_bounds__(256) void loop_alpha_kernel(const float* __restrict__ mean_attr,
                                                         const int* __restrict__ row_ptr,
                                                         const float* __restrict__ a_src,
                                                         const float* __restrict__ a_dst,
                                                         const float* __restrict__ we_i,
                                                         const float* __restrict__ be_i,
                                                         float* __restrict__ alphaL) {
    int g = threadIdx.x >> 5, c = threadIdx.x & 31;
    int n = blockIdx.x * 8 + g;  // NN % 8 == 0
    float ma = mean_attr[n * EDGE_F + c];
    float p[8];
    #pragma unroll
    for (int h = 0; h < 8; ++h) p[h] = ma * we_i[h * 32 + c];
    #pragma unroll
    for (int off = 16; off >= 1; off >>= 1)
        #pragma unroll
        for (int h = 0; h < 8; ++h) p[h] += __shfl_xor(p[h], off, 32);
    if (c < 8) {
        int h = c;
        int cn = row_ptr[n + 1] - row_ptr[n];
        float ae = cn > 0 ? p[h] + be_i[h] : 0.f;  // cnt==0 -> loop_attr==0 -> no bias
        float al = a_src[n * 8 + h] + a_dst[n * 8 + h] + ae;
        alphaL[n * 8 + h] = al > 0.f ? al : 0.2f * al;
    }
}

__device__ __forceinline__ float gelu_exact(float x) {
    return 0.5f * x * (1.f + erff(x * 0.70710678118654752f));
}

// ---------------------------------------------------------------- fused softmax-aggregate + bias + LN + GELU + residual
__global__ __launch_bounds__(64) void node_kernel(const float* __restrict__ xw,
                                                  float* __restrict__ alpha,
                                                  const float* __restrict__ alphaL,
                                                  const int* __restrict__ row_ptr,
                                                  const int* __restrict__ csr_src,
                                                  const int* __restrict__ csr_eid,
                                                  const float* __restrict__ h_prev,
                                                  float* __restrict__ h_next,
                                                  const float* __restrict__ cb,
                                                  const float* __restrict__ lg,
                                                  const float* __restrict__ lb, int first) {
    int n = blockIdx.x, l = threadIdx.x;
    int start = row_ptr[n], end = row_ptr[n + 1];

    // pass 1: max over {self-loop} ∪ incoming edges
    float m[8];
    #pragma unroll
    for (int h = 0; h < 8; ++h) m[h] = alphaL[n * 8 + h];
    for (int idx = start + l; idx < end; idx += 64) {
        int e = csr_eid[idx];
        #pragma unroll
        for (int h = 0; h < 8; ++h) m[h] = fmaxf(m[h], alpha[(size_t)e * 8 + h]);
    }
    #pragma unroll
    for (int off = 32; off >= 1; off >>= 1)
        #pragma unroll
        for (int h = 0; h < 8; ++h) m[h] = fmaxf(m[h], __shfl_xor(m[h], off, 64));

    // pass 2: exp + denom; overwrite alpha with exp weights
    float wl[8], s[8];
    #pragma unroll
    for (int h = 0; h < 8; ++h) {
        wl[h] = expf(alphaL[n * 8 + h] - m[h]);
        s[h] = (l == 0) ? wl[h] : 0.f;
    }
    for (int idx = start + l; idx < end; idx += 64) {
        int e = csr_eid[idx];
        #pragma unroll
        for (int h = 0; h < 8; ++h) {
            float w = expf(alpha[(size_t)e * 8 + h] - m[h]);
            alpha[(size_t)e * 8 + h] = w;
            s[h] += w;
        }
    }
    #pragma unroll
    for (int off = 32; off >= 1; off >>= 1)
        #pragma unroll
        for (int h = 0; h < 8; ++h) s[h] += __shfl_xor(s[h], off, 64);
    float inv[8];
    #pragma unroll
    for (int h = 0; h < 8; ++h) inv[h] = 1.f / (s[h] + 1e-16f);
    __syncthreads();  // make pass-2 alpha writes visible to all lanes

    // pass 3: weighted aggregate; lane owns channels l+64j
    float acc[4];
    #pragma unroll
    for (int j = 0; j < 4; ++j)
        acc[j] = wl[(l >> 5) + 2 * j] * xw[(size_t)n * HDIM + l + 64 * j];
    for (int idx = start; idx < end; ++idx) {
        int sn = csr_src[idx];
        int e = csr_eid[idx];
        const float* xr = xw + (size_t)sn * HDIM;
        #pragma unroll
        for (int j = 0; j < 4; ++j)
            acc[j] += alpha[(size_t)e * 8 + (l >> 5) + 2 * j] * xr[l + 64 * j];
    }
    #pragma unroll
    for (int j = 0; j < 4; ++j) {
        int ch = l + 64 * j;
        acc[j] = acc[j] * inv[(l >> 5) + 2 * j] + cb[ch];
    }

    // LayerNorm over 256 channels
    float part = acc[0] + acc[1] + acc[2] + acc[3];
    #pragma unroll
    for (int off = 32; off >= 1; off >>= 1) part += __shfl_xor(part, off, 64);
    float mu = part * (1.f / 256.f);
    float p2 = 0.f;
    #pragma unroll
    for (int j = 0; j < 4; ++j) {
        float d = acc[j] - mu;
        p2 += d * d;
    }
    #pragma unroll
    for (int off = 32; off >= 1; off >>= 1) p2 += __shfl_xor(p2, off, 64);
    float rstd = rsqrtf(p2 * (1.f / 256.f) + 1e-5f);
    #pragma unroll
    for (int j = 0; j < 4; ++j) {
        int ch = l + 64 * j;
        float y = (acc[j] - mu) * rstd * lg[ch] + lb[ch];
        float g = gelu_exact(y);
        h_next[(size_t)n * HDIM + ch] = g + (first ? 0.f : h_prev[(size_t)n * HDIM + ch]);
    }
}

// ---------------------------------------------------------------- graph readout + both MLP heads
__device__ __forceinline__ int lower_bound_dev(const int* a, int n, int v) {
    int lo = 0, hi = n;
    while (lo < hi) {
        int mid = (lo + hi) >> 1;
        if (a[mid] < v) lo = mid + 1; else hi = mid;
    }
    return lo;
}

__global__ __launch_bounds__(256) void readout_mlp_kernel(
    const float* __restrict__ h, const int* __restrict__ batch,
    const float* __restrict__ pw1, const float* __restrict__ pb1,
    const float* __restrict__ pw2, const float* __restrict__ pb2,
    const float* __restrict__ pw3, const float* __restrict__ pb3,
    const float* __restrict__ mw1, const float* __restrict__ mb1,
    const float* __restrict__ mw2, const float* __restrict__ mb2,
    const float* __restrict__ mw3, const float* __restrict__ mb3,
    float* __restrict__ out) {
    int g = blockIdx.x, t = threadIdx.x;
    __shared__ int se[2];
    __shared__ float xg[512];
    __shared__ float h1[256];
    __shared__ float h2[128];
    if (t == 0) {
        se[0] = lower_bound_dev(batch, NN, g);
        se[1] = lower_bound_dev(batch, NN, g + 1);
    }
    __syncthreads();
    int start = se[0], end = se[1];
    float acc = 0.f;
    for (int n = start; n < end; ++n) acc += h[(size_t)n * HDIM + t];
    float c = (float)(end - start);
    xg[t] = acc / fmaxf(c, 1.f);
    xg[256 + t] = acc;
    __syncthreads();

    for (int which = 0; which < 2; ++which) {
        const float* w1 = which ? mw1 : pw1; const float* b1 = which ? mb1 : pb1;
        const float* w2 = which ? mw2 : pw2; const float* b2 = which ? mb2 : pb2;
        const float* w3 = which ? mw3 : pw3; const float* b3 = which ? mb3 : pb3;
        {
            const float4* wr = (const float4*)(w1 + (size_t)t * 512);
            const float4* xv = (const float4*)xg;
            float s = 0.f;
            for (int k = 0; k < 128; ++k) {
                float4 w = wr[k], x = xv[k];
                s += w.x * x.x + w.y * x.y + w.z * x.z + w.w * x.w;
            }
            h1[t] = gelu_exact(s + b1[t]);
        }
        __syncthreads();
        if (t < 128) {
            const float4* wr = (const float4*)(w2 + (size_t)t * 256);
            const float4* xv = (const float4*)h1;
            float s = 0.f;
            for (int k = 0; k < 64; ++k) {
                float4 w = wr[k], x = xv[k];
                s += w.x * x.x + w.y * x.y + w.z * x.z + w.w * x.w;
            }
            h2[t] = gelu_exact(s + b2[t]);
        }
        __syncthreads();
        if (t < 3) {
            const float* wr = w3 + t * 128;
            float s = 0.f;
            for (int k = 0; k < 128; ++k) s += wr[k] * h2[k];
            s += b3[t];
            out[which * (NG * 3) + g * 3 + t] = 1.f / (1.f + expf(-s));
        }
        __syncthreads();
    }
}

// ---------------------------------------------------------------- launch
extern "C" void kernel_launch(void* const* d_in, const int* in_sizes, int n_in, void* d_out,
                              int out_size, void* d_ws, size_t ws_size, hipStream_t stream) {
    const float* x         = (const float*)d_in[0];
    const int*   ei        = (const int*)d_in[1];
    const int*   src       = ei;
    const int*   dst       = ei + NE;
    const float* edge_attr = (const float*)d_in[2];
    const int*   batch     = (const int*)d_in[3];
    const float* node_w    = (const float*)d_in[4];
    const float* node_b    = (const float*)d_in[5];
    const float* eew       = (const float*)d_in[6];
    const float* eeb       = (const float*)d_in[7];
    const float* lin_w     = (const float*)d_in[8];
    const float* att_src   = (const float*)d_in[9];
    const float* att_dst   = (const float*)d_in[10];
    const float* att_edge  = (const float*)d_in[11];
    const float* lin_edge_w= (const float*)d_in[12];
    const float* conv_b    = (const float*)d_in[13];
    const float* ln_g      = (const float*)d_in[14];
    const float* ln_b      = (const float*)d_in[15];
    const float* pw1 = (const float*)d_in[16]; const float* pb1 = (const float*)d_in[17];
    const float* pw2 = (const float*)d_in[18]; const float* pb2 = (const float*)d_in[19];
    const float* pw3 = (const float*)d_in[20]; const float* pb3 = (const float*)d_in[21];
    const float* mw1 = (const float*)d_in[22]; const float* mb1 = (const float*)d_in[23];
    const float* mw2 = (const float*)d_in[24]; const float* mb2 = (const float*)d_in[25];
    const float* mw3 = (const float*)d_in[26]; const float* mb3 = (const float*)d_in[27];
    float* out = (float*)d_out;

    float* wsf = (float*)d_ws;
    float* hA        = wsf; wsf += (size_t)NN * HDIM;
    float* hB        = wsf; wsf += (size_t)NN * HDIM;
    float* xw        = wsf; wsf += (size_t)NN * HDIM;
    float* alpha     = wsf; wsf += (size_t)NE * HEADS;
    float* alphaL    = wsf; wsf += (size_t)NN * HEADS;
    float* a_src     = wsf; wsf += (size_t)NN * HEADS;
    float* a_dst     = wsf; wsf += (size_t)NN * HEADS;
    float* mean_attr = wsf; wsf += (size_t)NN * EDGE_F;
    float* vbuf      = wsf; wsf += (size_t)LAYERS * HEADS * HDIM;
    float* webuf     = wsf; wsf += (size_t)LAYERS * HEADS * EDGE_F;
    float* bebuf     = wsf; wsf += 64;
    int* ibuf    = (int*)wsf;
    int* cnt     = ibuf; ibuf += NN + 16;
    int* row_ptr = ibuf; ibuf += NN + 16;
    int* pos     = ibuf; ibuf += NN + 16;
    int* csr_src = ibuf; ibuf += NE;
    int* csr_eid = ibuf; ibuf += NE;

    // CSR build
    hipMemsetAsync(cnt, 0, NN * sizeof(int), stream);
    count_kernel<<<(NE + 255) / 256, 256, 0, stream>>>(dst, cnt);
    scan_kernel<<<1, 1024, 0, stream>>>(cnt, row_ptr, pos);
    scatter_kernel<<<(NE + 255) / 256, 256, 0, stream>>>(src, dst, pos, csr_src, csr_eid);
    mean_attr_kernel<<<NN, 64, 0, stream>>>(edge_attr, row_ptr, csr_eid, mean_attr);

    // fold edge-attention weights
    v_kernel<<<(LAYERS * HEADS * HDIM + 255) / 256, 256, 0, stream>>>(att_edge, lin_edge_w, vbuf);
    we_kernel<<<(LAYERS * HEADS * EDGE_F + LAYERS * HEADS + 255) / 256, 256, 0, stream>>>(
        vbuf, eew, eeb, webuf, bebuf);

    // node embedding: hA = x @ node_w.T + node_b
    {
        dim3 grid(HDIM / 64, (NN + 63) / 64);
        gemm_bt<<<grid, 256, 0, stream>>>(x, node_w, node_b, hA, NN, NODE_F, HDIM);
    }

    float* cur = hA;
    float* nxt = hB;
    for (int i = 0; i < LAYERS; ++i) {
        dim3 grid(HDIM / 64, (NN + 63) / 64);
        gemm_bt<<<grid, 256, 0, stream>>>(cur, lin_w + (size_t)i * HDIM * HDIM, nullptr, xw,
                                          NN, HDIM, HDIM);
        asrcdst_kernel<<<(NN * HEADS + 255) / 256, 256, 0, stream>>>(
            xw, att_src + i * HEADS * 32, att_dst + i * HEADS * 32, a_src, a_dst);
        edge_alpha_kernel<<<NE / 8, 256, 0, stream>>>(src, dst, edge_attr, a_src, a_dst,
                                                      webuf + i * HEADS * EDGE_F,
                                                      bebuf + i * HEADS, alpha);
        loop_alpha_kernel<<<NN / 8, 256, 0, stream>>>(mean_attr, row_ptr, a_src, a_dst,
                                                      webuf + i * HEADS * EDGE_F,
                                                      bebuf + i * HEADS, alphaL);
        node_kernel<<<NN, 64, 0, stream>>>(xw, alpha, alphaL, row_ptr, csr_src, csr_eid, cur,
                                           nxt, conv_b + i * HDIM, ln_g + i * HDIM,
                                           ln_b + i * HDIM, i == 0 ? 1 : 0);
        float* tmp = cur; cur = nxt; nxt = tmp;
    }

    readout_mlp_kernel<<<NG, 256, 0, stream>>>(cur, batch, pw1, pb1, pw2, pb2, pw3, pb3, mw1,
                                               mb1, mw2, mb2, mw3, mb3, out);
}

// Round 2
// 1268.671 us; speedup vs baseline: 1.1997x; 1.1997x over previous
//
#include <hip/hip_runtime.h>
#include <math.h>

#define NN 10000
#define NE 320000
#define NODE_F 64
#define EDGE_F 32
#define HDIM 256
#define HEADS 8
#define LAYERS 6
#define NG 16

typedef __attribute__((ext_vector_type(8))) short short8;
typedef __attribute__((ext_vector_type(4))) float float4v;

// ---------------------------------------------------------------- CSR build
__global__ void count_kernel(const int* __restrict__ dst, int* __restrict__ cnt) {
    int e = blockIdx.x * 256 + threadIdx.x;
    if (e < NE) atomicAdd(&cnt[dst[e]], 1);
}

__global__ void scan_kernel(const int* __restrict__ cnt, int* __restrict__ row_ptr,
                            int* __restrict__ pos) {
    __shared__ int part[1024];
    int t = threadIdx.x;
    const int chunk = (NN + 1023) / 1024;  // 10
    int lo = t * chunk, hi = min(NN, lo + chunk);
    int s = 0;
    for (int i = lo; i < hi; ++i) s += cnt[i];
    part[t] = s;
    __syncthreads();
    for (int off = 1; off < 1024; off <<= 1) {
        int v = (t >= off) ? part[t - off] : 0;
        __syncthreads();
        part[t] += v;
        __syncthreads();
    }
    int base = (t == 0) ? 0 : part[t - 1];
    for (int i = lo; i < hi; ++i) {
        row_ptr[i] = base;
        pos[i] = base;
        base += cnt[i];
    }
    if (t == 1023) row_ptr[NN] = part[1023];
}

__global__ void scatter_kernel(const int* __restrict__ src, const int* __restrict__ dst,
                               int* __restrict__ pos, int* __restrict__ csr_src,
                               int* __restrict__ csr_eid) {
    int e = blockIdx.x * 256 + threadIdx.x;
    if (e >= NE) return;
    int d = dst[e];
    int idx = atomicAdd(&pos[d], 1);
    csr_src[idx] = src[e];
    csr_eid[idx] = e;
}

// mean of incoming raw edge_attr per node (PyG fill_value='mean' precursor)
__global__ __launch_bounds__(64) void mean_attr_kernel(const float* __restrict__ edge_attr,
                                                       const int* __restrict__ row_ptr,
                                                       const int* __restrict__ csr_eid,
                                                       float* __restrict__ mean_attr) {
    int n = blockIdx.x, l = threadIdx.x;
    if (l >= EDGE_F) return;
    int start = row_ptr[n], end = row_ptr[n + 1];
    float s = 0.f;
    for (int idx = start; idx < end; ++idx) s += edge_attr[(size_t)csr_eid[idx] * EDGE_F + l];
    int c = end - start;
    mean_attr[n * EDGE_F + l] = c > 0 ? s / (float)c : 0.f;
}

// ---------------------------------------------------------------- edge-attn weight folding
__global__ void v_kernel(const float* __restrict__ att_edge, const float* __restrict__ lin_edge_w,
                         float* __restrict__ v) {
    int idx = blockIdx.x * 256 + threadIdx.x;
    if (idx >= LAYERS * HEADS * HDIM) return;
    int i = idx / (HEADS * HDIM);
    int r = idx % (HEADS * HDIM);
    int h = r / HDIM, k = r % HDIM;
    float s = 0.f;
    #pragma unroll 4
    for (int o = 0; o < 32; ++o)
        s += att_edge[(i * HEADS + h) * 32 + o] *
             lin_edge_w[((size_t)i * HDIM + h * 32 + o) * HDIM + k];
    v[idx] = s;
}

__global__ void we_kernel(const float* __restrict__ v, const float* __restrict__ edge_emb_w,
                          const float* __restrict__ edge_emb_b, float* __restrict__ we,
                          float* __restrict__ be) {
    int idx = blockIdx.x * 256 + threadIdx.x;
    if (idx < LAYERS * HEADS * EDGE_F) {
        int i = idx / (HEADS * EDGE_F);
        int r = idx % (HEADS * EDGE_F);
        int h = r >> 5, f = r & 31;
        float s = 0.f;
        for (int k = 0; k < HDIM; ++k)
            s += v[(i * HEADS + h) * HDIM + k] * edge_emb_w[k * EDGE_F + f];
        we[idx] = s;
    } else if (idx < LAYERS * HEADS * EDGE_F + LAYERS * HEADS) {
        int j = idx - LAYERS * HEADS * EDGE_F;
        int i = j / HEADS, h = j % HEADS;
        float s = 0.f;
        for (int k = 0; k < HDIM; ++k) s += v[(i * HEADS + h) * HDIM + k] * edge_emb_b[k];
        be[j] = s;
    }
}

// ---------------------------------------------------------------- bf16x3 MFMA GEMM
// C[n,j] = sum_k A[n,k]*B[j,k] (+bias), f32 in/out, internally split a=hi+lo bf16,
// acc += hi*hi + hi*lo + lo*hi  (drops lo*lo ~ 2^-16 rel err)
__device__ __forceinline__ ushort f2bf(float f) {
    union { float f; unsigned u; } v; v.f = f;
    unsigned u = v.u;
    return (ushort)((u + 0x7fffu + ((u >> 16) & 1u)) >> 16);
}
__device__ __forceinline__ float bf2f(ushort b) {
    union { unsigned u; float f; } v; v.u = ((unsigned)b) << 16; return v.f;
}

__global__ __launch_bounds__(256) void gemm_mfma(const float* __restrict__ A,
                                                 const float* __restrict__ B,
                                                 const float* __restrict__ bias,
                                                 float* __restrict__ C, int N, int K, int J) {
    // BM=64, BN=64, BK=32. LDS rows padded to 40 shorts (80B, 16B-aligned, 2-way banks = free)
    __shared__ ushort Ah[64][40], Al[64][40], Bh[64][40], Bl[64][40];
    int nb = blockIdx.y * 64, jb = blockIdx.x * 64;
    int t = threadIdx.x;
    int w = t >> 6, l = t & 63;
    int srow = t >> 2, sq = (t & 3) * 8;       // staging: row 0..63, col group of 8
    int fr = l & 15, fq = (l >> 4) * 8;        // fragment: row/col base, k offset

    float4v acc[4] = {};
    for (int kt = 0; kt < K; kt += 32) {
        // stage A
        {
            float va[8] = {};
            int gr = nb + srow;
            if (gr < N) {
                const float4* p = (const float4*)(A + (size_t)gr * K + kt + sq);
                float4 x0 = p[0], x1 = p[1];
                va[0] = x0.x; va[1] = x0.y; va[2] = x0.z; va[3] = x0.w;
                va[4] = x1.x; va[5] = x1.y; va[6] = x1.z; va[7] = x1.w;
            }
            ushort hh[8], ll[8];
            #pragma unroll
            for (int j = 0; j < 8; ++j) {
                hh[j] = f2bf(va[j]);
                ll[j] = f2bf(va[j] - bf2f(hh[j]));
            }
            *(short8*)&Ah[srow][sq] = *(short8*)hh;
            *(short8*)&Al[srow][sq] = *(short8*)ll;
        }
        // stage B (J is a multiple of 64, rows always valid)
        {
            const float4* p = (const float4*)(B + (size_t)(jb + srow) * K + kt + sq);
            float4 x0 = p[0], x1 = p[1];
            float vb[8] = {x0.x, x0.y, x0.z, x0.w, x1.x, x1.y, x1.z, x1.w};
            ushort hh[8], ll[8];
            #pragma unroll
            for (int j = 0; j < 8; ++j) {
                hh[j] = f2bf(vb[j]);
                ll[j] = f2bf(vb[j] - bf2f(hh[j]));
            }
            *(short8*)&Bh[srow][sq] = *(short8*)hh;
            *(short8*)&Bl[srow][sq] = *(short8*)ll;
        }
        __syncthreads();
        short8 bh = *(const short8*)&Bh[w * 16 + fr][fq];
        short8 bl = *(const short8*)&Bl[w * 16 + fr][fq];
        #pragma unroll
        for (int mt = 0; mt < 4; ++mt) {
            short8 ah = *(const short8*)&Ah[mt * 16 + fr][fq];
            short8 al = *(const short8*)&Al[mt * 16 + fr][fq];
            acc[mt] = __builtin_amdgcn_mfma_f32_16x16x32_bf16(ah, bh, acc[mt], 0, 0, 0);
            acc[mt] = __builtin_amdgcn_mfma_f32_16x16x32_bf16(ah, bl, acc[mt], 0, 0, 0);
            acc[mt] = __builtin_amdgcn_mfma_f32_16x16x32_bf16(al, bh, acc[mt], 0, 0, 0);
        }
        __syncthreads();
    }
    // C/D layout: col = lane&15, row = (lane>>4)*4 + reg
    int col = jb + w * 16 + fr;
    float bv = bias ? bias[col] : 0.f;
    #pragma unroll
    for (int mt = 0; mt < 4; ++mt) {
        #pragma unroll
        for (int r = 0; r < 4; ++r) {
            int row = nb + mt * 16 + (l >> 4) * 4 + r;
            if (row < N) C[(size_t)row * J + col] = acc[mt][r] + bv;
        }
    }
}

// ---------------------------------------------------------------- per-node a_src/a_dst from xw
__global__ void asrcdst_kernel(const float* __restrict__ xw, const float* __restrict__ att_s,
                               const float* __restrict__ att_d, float* __restrict__ a_src,
                               float* __restrict__ a_dst) {
    int tid = blockIdx.x * 256 + threadIdx.x;
    if (tid >= NN * HEADS) return;
    int n = tid >> 3, h = tid & 7;
    const float4* xv = (const float4*)(xw + (size_t)n * HDIM + h * 32);
    const float4* sv = (const float4*)(att_s + h * 32);
    const float4* dv = (const float4*)(att_d + h * 32);
    float s1 = 0.f, s2 = 0.f;
    #pragma unroll
    for (int q = 0; q < 8; ++q) {
        float4 xx = xv[q], aa = sv[q], bb = dv[q];
        s1 += xx.x * aa.x + xx.y * aa.y + xx.z * aa.z + xx.w * aa.w;
        s2 += xx.x * bb.x + xx.y * bb.y + xx.z * bb.z + xx.w * bb.w;
    }
    a_src[tid] = s1;
    a_dst[tid] = s2;
}

// ---------------------------------------------------------------- per-edge alpha
__global__ __launch_bounds__(256) void edge_alpha_kernel(const int* __restrict__ src,
                                                         const int* __restrict__ dst,
                                                         const float* __restrict__ edge_attr,
                                                         const float* __restrict__ a_src,
                                                         const float* __restrict__ a_dst,
                                                         const float* __restrict__ we_i,
                                                         const float* __restrict__ be_i,
                                                         float* __restrict__ alpha) {
    int g = threadIdx.x >> 5, c = threadIdx.x & 31;
    int e = blockIdx.x * 8 + g;  // NE % 8 == 0
    float ea = edge_attr[(size_t)e * EDGE_F + c];
    float p[8];
    #pragma unroll
    for (int h = 0; h < 8; ++h) p[h] = ea * we_i[h * 32 + c];
    #pragma unroll
    for (int off = 16; off >= 1; off >>= 1)
        #pragma unroll
        for (int h = 0; h < 8; ++h) p[h] += __shfl_xor(p[h], off, 32);
    if (c < 8) {
        int h = c, s = src[e], d = dst[e];
        float al = a_src[s * 8 + h] + a_dst[d * 8 + h] + p[h] + be_i[h];
        alpha[(size_t)e * 8 + h] = al > 0.f ? al : 0.2f * al;
    }
}

__global__ __launch_bounds__(256) void loop_alpha_kernel(const float* __restrict__ mean_attr,
                                                         const int* __restrict__ row_ptr,
                                                         const float* __restrict__ a_src,
                                                         const float* __restrict__ a_dst,
                                                         const float* __restrict__ we_i,
                                                         const float* __restrict__ be_i,
                                                         float* __restrict__ alphaL) {
    int g = threadIdx.x >> 5, c = threadIdx.x & 31;
    int n = blockIdx.x * 8 + g;  // NN % 8 == 0
    float ma = mean_attr[n * EDGE_F + c];
    float p[8];
    #pragma unroll
    for (int h = 0; h < 8; ++h) p[h] = ma * we_i[h * 32 + c];
    #pragma unroll
    for (int off = 16; off >= 1; off >>= 1)
        #pragma unroll
        for (int h = 0; h < 8; ++h) p[h] += __shfl_xor(p[h], off, 32);
    if (c < 8) {
        int h = c;
        int cn = row_ptr[n + 1] - row_ptr[n];
        float ae = cn > 0 ? p[h] + be_i[h] : 0.f;
        float al = a_src[n * 8 + h] + a_dst[n * 8 + h] + ae;
        alphaL[n * 8 + h] = al > 0.f ? al : 0.2f * al;
    }
}

__device__ __forceinline__ float gelu_exact(float x) {
    return 0.5f * x * (1.f + erff(x * 0.70710678118654752f));
}

// ---------------------------------------------------------------- fused softmax-aggregate + bias + LN + GELU + residual
__global__ __launch_bounds__(64) void node_kernel(const float* __restrict__ xw,
                                                  float* __restrict__ alpha,
                                                  const float* __restrict__ alphaL,
                                                  const int* __restrict__ row_ptr,
                                                  const int* __restrict__ csr_src,
                                                  const int* __restrict__ csr_eid,
                                                  const float* __restrict__ h_prev,
                                                  float* __restrict__ h_next,
                                                  const float* __restrict__ cb,
                                                  const float* __restrict__ lg,
                                                  const float* __restrict__ lb, int first) {
    int n = blockIdx.x, l = threadIdx.x;
    int start = row_ptr[n], end = row_ptr[n + 1];

    float m[8];
    #pragma unroll
    for (int h = 0; h < 8; ++h) m[h] = alphaL[n * 8 + h];
    for (int idx = start + l; idx < end; idx += 64) {
        int e = csr_eid[idx];
        #pragma unroll
        for (int h = 0; h < 8; ++h) m[h] = fmaxf(m[h], alpha[(size_t)e * 8 + h]);
    }
    #pragma unroll
    for (int off = 32; off >= 1; off >>= 1)
        #pragma unroll
        for (int h = 0; h < 8; ++h) m[h] = fmaxf(m[h], __shfl_xor(m[h], off, 64));

    float wl[8], s[8];
    #pragma unroll
    for (int h = 0; h < 8; ++h) {
        wl[h] = expf(alphaL[n * 8 + h] - m[h]);
        s[h] = (l == 0) ? wl[h] : 0.f;
    }
    for (int idx = start + l; idx < end; idx += 64) {
        int e = csr_eid[idx];
        #pragma unroll
        for (int h = 0; h < 8; ++h) {
            float w = expf(alpha[(size_t)e * 8 + h] - m[h]);
            alpha[(size_t)e * 8 + h] = w;
            s[h] += w;
        }
    }
    #pragma unroll
    for (int off = 32; off >= 1; off >>= 1)
        #pragma unroll
        for (int h = 0; h < 8; ++h) s[h] += __shfl_xor(s[h], off, 64);
    float inv[8];
    #pragma unroll
    for (int h = 0; h < 8; ++h) inv[h] = 1.f / (s[h] + 1e-16f);
    __syncthreads();

    float acc[4];
    #pragma unroll
    for (int j = 0; j < 4; ++j)
        acc[j] = wl[(l >> 5) + 2 * j] * xw[(size_t)n * HDIM + l + 64 * j];
    for (int idx = start; idx < end; ++idx) {
        int sn = csr_src[idx];
        int e = csr_eid[idx];
        const float* xr = xw + (size_t)sn * HDIM;
        #pragma unroll
        for (int j = 0; j < 4; ++j)
            acc[j] += alpha[(size_t)e * 8 + (l >> 5) + 2 * j] * xr[l + 64 * j];
    }
    #pragma unroll
    for (int j = 0; j < 4; ++j) {
        int ch = l + 64 * j;
        acc[j] = acc[j] * inv[(l >> 5) + 2 * j] + cb[ch];
    }

    float part = acc[0] + acc[1] + acc[2] + acc[3];
    #pragma unroll
    for (int off = 32; off >= 1; off >>= 1) part += __shfl_xor(part, off, 64);
    float mu = part * (1.f / 256.f);
    float p2 = 0.f;
    #pragma unroll
    for (int j = 0; j < 4; ++j) {
        float d = acc[j] - mu;
        p2 += d * d;
    }
    #pragma unroll
    for (int off = 32; off >= 1; off >>= 1) p2 += __shfl_xor(p2, off, 64);
    float rstd = rsqrtf(p2 * (1.f / 256.f) + 1e-5f);
    #pragma unroll
    for (int j = 0; j < 4; ++j) {
        int ch = l + 64 * j;
        float y = (acc[j] - mu) * rstd * lg[ch] + lb[ch];
        float g = gelu_exact(y);
        h_next[(size_t)n * HDIM + ch] = g + (first ? 0.f : h_prev[(size_t)n * HDIM + ch]);
    }
}

// ---------------------------------------------------------------- graph readout: parallel segment sum
__global__ __launch_bounds__(256) void graph_sum_kernel(const float* __restrict__ h,
                                                        const int* __restrict__ batch,
                                                        float* __restrict__ sums) {
    int t = threadIdx.x;
    int n0 = blockIdx.x * 64;
    int n1 = min(NN, n0 + 64);
    float acc = 0.f;
    int cur = batch[n0];
    for (int n = n0; n < n1; ++n) {
        int b = batch[n];
        if (b != cur) {
            atomicAdd(&sums[cur * HDIM + t], acc);
            acc = 0.f;
            cur = b;
        }
        acc += h[(size_t)n * HDIM + t];
    }
    atomicAdd(&sums[cur * HDIM + t], acc);
}

__device__ __forceinline__ int lower_bound_dev(const int* a, int n, int v) {
    int lo = 0, hi = n;
    while (lo < hi) {
        int mid = (lo + hi) >> 1;
        if (a[mid] < v) lo = mid + 1; else hi = mid;
    }
    return lo;
}

__global__ __launch_bounds__(256) void readout_mlp_kernel(
    const float* __restrict__ sums, const int* __restrict__ batch,
    const float* __restrict__ pw1, const float* __restrict__ pb1,
    const float* __restrict__ pw2, const float* __restrict__ pb2,
    const float* __restrict__ pw3, const float* __restrict__ pb3,
    const float* __restrict__ mw1, const float* __restrict__ mb1,
    const float* __restrict__ mw2, const float* __restrict__ mb2,
    const float* __restrict__ mw3, const float* __restrict__ mb3,
    float* __restrict__ out) {
    int g = blockIdx.x, t = threadIdx.x;
    __shared__ int se[2];
    __shared__ float xg[512];
    __shared__ float h1[256];
    __shared__ float h2[128];
    if (t == 0) {
        se[0] = lower_bound_dev(batch, NN, g);
        se[1] = lower_bound_dev(batch, NN, g + 1);
    }
    __syncthreads();
    float c = (float)(se[1] - se[0]);
    float s = sums[g * HDIM + t];
    xg[t] = s / fmaxf(c, 1.f);
    xg[256 + t] = s;
    __syncthreads();

    for (int which = 0; which < 2; ++which) {
        const float* w1 = which ? mw1 : pw1; const float* b1 = which ? mb1 : pb1;
        const float* w2 = which ? mw2 : pw2; const float* b2 = which ? mb2 : pb2;
        const float* w3 = which ? mw3 : pw3; const float* b3 = which ? mb3 : pb3;
        {
            const float4* wr = (const float4*)(w1 + (size_t)t * 512);
            const float4* xv = (const float4*)xg;
            float s1 = 0.f;
            for (int k = 0; k < 128; ++k) {
                float4 w = wr[k], x = xv[k];
                s1 += w.x * x.x + w.y * x.y + w.z * x.z + w.w * x.w;
            }
            h1[t] = gelu_exact(s1 + b1[t]);
        }
        __syncthreads();
        if (t < 128) {
            const float4* wr = (const float4*)(w2 + (size_t)t * 256);
            const float4* xv = (const float4*)h1;
            float s1 = 0.f;
            for (int k = 0; k < 64; ++k) {
                float4 w = wr[k], x = xv[k];
                s1 += w.x * x.x + w.y * x.y + w.z * x.z + w.w * x.w;
            }
            h2[t] = gelu_exact(s1 + b2[t]);
        }
        __syncthreads();
        if (t < 3) {
            const float* wr = w3 + t * 128;
            float s1 = 0.f;
            for (int k = 0; k < 128; ++k) s1 += wr[k] * h2[k];
            s1 += b3[t];
            out[which * (NG * 3) + g * 3 + t] = 1.f / (1.f + expf(-s1));
        }
        __syncthreads();
    }
}

// ---------------------------------------------------------------- launch
extern "C" void kernel_launch(void* const* d_in, const int* in_sizes, int n_in, void* d_out,
                              int out_size, void* d_ws, size_t ws_size, hipStream_t stream) {
    const float* x         = (const float*)d_in[0];
    const int*   ei        = (const int*)d_in[1];
    const int*   src       = ei;
    const int*   dst       = ei + NE;
    const float* edge_attr = (const float*)d_in[2];
    const int*   batch     = (const int*)d_in[3];
    const float* node_w    = (const float*)d_in[4];
    const float* node_b    = (const float*)d_in[5];
    const float* eew       = (const float*)d_in[6];
    const float* eeb       = (const float*)d_in[7];
    const float* lin_w     = (const float*)d_in[8];
    const float* att_src   = (const float*)d_in[9];
    const float* att_dst   = (const float*)d_in[10];
    const float* att_edge  = (const float*)d_in[11];
    const float* lin_edge_w= (const float*)d_in[12];
    const float* conv_b    = (const float*)d_in[13];
    const float* ln_g      = (const float*)d_in[14];
    const float* ln_b      = (const float*)d_in[15];
    const float* pw1 = (const float*)d_in[16]; const float* pb1 = (const float*)d_in[17];
    const float* pw2 = (const float*)d_in[18]; const float* pb2 = (const float*)d_in[19];
    const float* pw3 = (const float*)d_in[20]; const float* pb3 = (const float*)d_in[21];
    const float* mw1 = (const float*)d_in[22]; const float* mb1 = (const float*)d_in[23];
    const float* mw2 = (const float*)d_in[24]; const float* mb2 = (const float*)d_in[25];
    const float* mw3 = (const float*)d_in[26]; const float* mb3 = (const float*)d_in[27];
    float* out = (float*)d_out;

    float* wsf = (float*)d_ws;
    float* hA        = wsf; wsf += (size_t)NN * HDIM;
    float* hB        = wsf; wsf += (size_t)NN * HDIM;
    float* xw        = wsf; wsf += (size_t)NN * HDIM;
    float* alpha     = wsf; wsf += (size_t)NE * HEADS;
    float* alphaL    = wsf; wsf += (size_t)NN * HEADS;
    float* a_src     = wsf; wsf += (size_t)NN * HEADS;
    float* a_dst     = wsf; wsf += (size_t)NN * HEADS;
    float* mean_attr = wsf; wsf += (size_t)NN * EDGE_F;
    float* vbuf      = wsf; wsf += (size_t)LAYERS * HEADS * HDIM;
    float* webuf     = wsf; wsf += (size_t)LAYERS * HEADS * EDGE_F;
    float* bebuf     = wsf; wsf += 64;
    float* sums      = wsf; wsf += (size_t)NG * HDIM;
    int* ibuf    = (int*)wsf;
    int* cnt     = ibuf; ibuf += NN + 16;
    int* row_ptr = ibuf; ibuf += NN + 16;
    int* pos     = ibuf; ibuf += NN + 16;
    int* csr_src = ibuf; ibuf += NE;
    int* csr_eid = ibuf; ibuf += NE;

    // CSR build
    hipMemsetAsync(cnt, 0, NN * sizeof(int), stream);
    count_kernel<<<(NE + 255) / 256, 256, 0, stream>>>(dst, cnt);
    scan_kernel<<<1, 1024, 0, stream>>>(cnt, row_ptr, pos);
    scatter_kernel<<<(NE + 255) / 256, 256, 0, stream>>>(src, dst, pos, csr_src, csr_eid);
    mean_attr_kernel<<<NN, 64, 0, stream>>>(edge_attr, row_ptr, csr_eid, mean_attr);

    // fold edge-attention weights
    v_kernel<<<(LAYERS * HEADS * HDIM + 255) / 256, 256, 0, stream>>>(att_edge, lin_edge_w, vbuf);
    we_kernel<<<(LAYERS * HEADS * EDGE_F + LAYERS * HEADS + 255) / 256, 256, 0, stream>>>(
        vbuf, eew, eeb, webuf, bebuf);

    // node embedding: hA = x @ node_w.T + node_b
    {
        dim3 grid(HDIM / 64, (NN + 63) / 64);
        gemm_mfma<<<grid, 256, 0, stream>>>(x, node_w, node_b, hA, NN, NODE_F, HDIM);
    }

    float* cur = hA;
    float* nxt = hB;
    for (int i = 0; i < LAYERS; ++i) {
        dim3 grid(HDIM / 64, (NN + 63) / 64);
        gemm_mfma<<<grid, 256, 0, stream>>>(cur, lin_w + (size_t)i * HDIM * HDIM, nullptr, xw,
                                            NN, HDIM, HDIM);
        asrcdst_kernel<<<(NN * HEADS + 255) / 256, 256, 0, stream>>>(
            xw, att_src + i * HEADS * 32, att_dst + i * HEADS * 32, a_src, a_dst);
        edge_alpha_kernel<<<NE / 8, 256, 0, stream>>>(src, dst, edge_attr, a_src, a_dst,
                                                      webuf + i * HEADS * EDGE_F,
                                                      bebuf + i * HEADS, alpha);
        loop_alpha_kernel<<<NN / 8, 256, 0, stream>>>(mean_attr, row_ptr, a_src, a_dst,
                                                      webuf + i * HEADS * EDGE_F,
                                                      bebuf + i * HEADS, alphaL);
        node_kernel<<<NN, 64, 0, stream>>>(xw, alpha, alphaL, row_ptr, csr_src, csr_eid, cur,
                                           nxt, conv_b + i * HDIM, ln_g + i * HDIM,
                                           ln_b + i * HDIM, i == 0 ? 1 : 0);
        float* tmp = cur; cur = nxt; nxt = tmp;
    }

    hipMemsetAsync(sums, 0, NG * HDIM * sizeof(float), stream);
    graph_sum_kernel<<<(NN + 63) / 64, 256, 0, stream>>>(cur, batch, sums);
    readout_mlp_kernel<<<NG, 256, 0, stream>>>(sums, batch, pw1, pb1, pw2, pb2, pw3, pb3, mw1,
                                               mb1, mw2, mb2, mw3, mb3, out);
}

// Round 3
// 844.816 us; speedup vs baseline: 1.8016x; 1.5017x over previous
//
#include <hip/hip_runtime.h>
#include <math.h>

#define NN 10000
#define NE 320000
#define NODE_F 64
#define EDGE_F 32
#define HDIM 256
#define HEADS 8
#define LAYERS 6
#define NG 16
#define DCAP 128

typedef __attribute__((ext_vector_type(8))) short short8;
typedef __attribute__((ext_vector_type(4))) float float4v;

// ---------------------------------------------------------------- CSR build
__global__ void count_kernel(const int* __restrict__ dst, int* __restrict__ cnt) {
    int e = blockIdx.x * 256 + threadIdx.x;
    if (e < NE) atomicAdd(&cnt[dst[e]], 1);
}

__global__ void scan_kernel(const int* __restrict__ cnt, int* __restrict__ row_ptr,
                            int* __restrict__ pos) {
    __shared__ int part[1024];
    int t = threadIdx.x;
    const int chunk = (NN + 1023) / 1024;  // 10
    int lo = t * chunk, hi = min(NN, lo + chunk);
    int s = 0;
    for (int i = lo; i < hi; ++i) s += cnt[i];
    part[t] = s;
    __syncthreads();
    for (int off = 1; off < 1024; off <<= 1) {
        int v = (t >= off) ? part[t - off] : 0;
        __syncthreads();
        part[t] += v;
        __syncthreads();
    }
    int base = (t == 0) ? 0 : part[t - 1];
    for (int i = lo; i < hi; ++i) {
        row_ptr[i] = base;
        pos[i] = base;
        base += cnt[i];
    }
    if (t == 1023) row_ptr[NN] = part[1023];
}

__global__ void scatter_kernel(const int* __restrict__ src, const int* __restrict__ dst,
                               int* __restrict__ pos, int* __restrict__ csr_src,
                               int* __restrict__ csr_eid) {
    int e = blockIdx.x * 256 + threadIdx.x;
    if (e >= NE) return;
    int d = dst[e];
    int idx = atomicAdd(&pos[d], 1);
    csr_src[idx] = src[e];
    csr_eid[idx] = e;
}

// mean of incoming raw edge_attr per node (PyG fill_value='mean')
__global__ __launch_bounds__(64) void mean_attr_kernel(const float* __restrict__ edge_attr,
                                                       const int* __restrict__ row_ptr,
                                                       const int* __restrict__ csr_eid,
                                                       float* __restrict__ mean_attr) {
    int n = blockIdx.x, l = threadIdx.x;
    if (l >= EDGE_F) return;
    int start = row_ptr[n], end = row_ptr[n + 1];
    float s = 0.f;
    for (int idx = start; idx < end; ++idx) s += edge_attr[(size_t)csr_eid[idx] * EDGE_F + l];
    int c = end - start;
    mean_attr[n * EDGE_F + l] = c > 0 ? s / (float)c : 0.f;
}

// ---------------------------------------------------------------- edge-attn weight folding
__global__ void v_kernel(const float* __restrict__ att_edge, const float* __restrict__ lin_edge_w,
                         float* __restrict__ v) {
    int idx = blockIdx.x * 256 + threadIdx.x;
    if (idx >= LAYERS * HEADS * HDIM) return;
    int i = idx / (HEADS * HDIM);
    int r = idx % (HEADS * HDIM);
    int h = r / HDIM, k = r % HDIM;
    float s = 0.f;
    #pragma unroll 4
    for (int o = 0; o < 32; ++o)
        s += att_edge[(i * HEADS + h) * 32 + o] *
             lin_edge_w[((size_t)i * HDIM + h * 32 + o) * HDIM + k];
    v[idx] = s;
}

__global__ void we_kernel(const float* __restrict__ v, const float* __restrict__ edge_emb_w,
                          const float* __restrict__ edge_emb_b, float* __restrict__ we,
                          float* __restrict__ be) {
    int idx = blockIdx.x * 256 + threadIdx.x;
    if (idx < LAYERS * HEADS * EDGE_F) {
        int i = idx / (HEADS * EDGE_F);
        int r = idx % (HEADS * EDGE_F);
        int h = r >> 5, f = r & 31;
        float s = 0.f;
        for (int k = 0; k < HDIM; ++k)
            s += v[(i * HEADS + h) * HDIM + k] * edge_emb_w[k * EDGE_F + f];
        we[idx] = s;
    } else if (idx < LAYERS * HEADS * EDGE_F + LAYERS * HEADS) {
        int j = idx - LAYERS * HEADS * EDGE_F;
        int i = j / HEADS, h = j % HEADS;
        float s = 0.f;
        for (int k = 0; k < HDIM; ++k) s += v[(i * HEADS + h) * HDIM + k] * edge_emb_b[k];
        be[j] = s;
    }
}

// ---------------------------------------------------------------- layer-invariant logit partials
// preE[l][idx][h] = edge_attr[csr_eid[idx]] . we[l,h] + be[l,h]   (CSR order!)
__global__ __launch_bounds__(256) void preE_kernel(const int* __restrict__ csr_eid,
                                                   const float* __restrict__ edge_attr,
                                                   const float* __restrict__ we,
                                                   const float* __restrict__ be,
                                                   float* __restrict__ preE) {
    __shared__ float swe[LAYERS * HEADS * EDGE_F];
    __shared__ float sbe[LAYERS * HEADS];
    int t = threadIdx.x;
    for (int i = t; i < LAYERS * HEADS * EDGE_F; i += 256) swe[i] = we[i];
    for (int i = t; i < LAYERS * HEADS; i += 256) sbe[i] = be[i];
    __syncthreads();
    int idx = blockIdx.x * 256 + t;
    if (idx >= NE) return;
    int eid = csr_eid[idx];
    float ea[32];
    const float4* p = (const float4*)(edge_attr + (size_t)eid * EDGE_F);
    #pragma unroll
    for (int q = 0; q < 8; ++q) {
        float4 v = p[q];
        ea[q * 4] = v.x; ea[q * 4 + 1] = v.y; ea[q * 4 + 2] = v.z; ea[q * 4 + 3] = v.w;
    }
    for (int li = 0; li < LAYERS; ++li) {
        float out[8];
        #pragma unroll
        for (int h = 0; h < 8; ++h) {
            const float* wr = &swe[(li * HEADS + h) * EDGE_F];
            float s = sbe[li * HEADS + h];
            #pragma unroll
            for (int c = 0; c < 32; ++c) s += ea[c] * wr[c];
            out[h] = s;
        }
        float4* dstp = (float4*)(preE + ((size_t)li * NE + idx) * 8);
        dstp[0] = make_float4(out[0], out[1], out[2], out[3]);
        dstp[1] = make_float4(out[4], out[5], out[6], out[7]);
    }
}

// preL[l][n][h] = (deg>0) ? mean_attr[n] . we[l,h] + be[l,h] : 0
__global__ __launch_bounds__(256) void preL_kernel(const float* __restrict__ mean_attr,
                                                   const int* __restrict__ row_ptr,
                                                   const float* __restrict__ we,
                                                   const float* __restrict__ be,
                                                   float* __restrict__ preL) {
    __shared__ float swe[LAYERS * HEADS * EDGE_F];
    __shared__ float sbe[LAYERS * HEADS];
    int t = threadIdx.x;
    for (int i = t; i < LAYERS * HEADS * EDGE_F; i += 256) swe[i] = we[i];
    for (int i = t; i < LAYERS * HEADS; i += 256) sbe[i] = be[i];
    __syncthreads();
    int n = blockIdx.x * 256 + t;
    if (n >= NN) return;
    int deg = row_ptr[n + 1] - row_ptr[n];
    float ea[32];
    const float4* p = (const float4*)(mean_attr + (size_t)n * EDGE_F);
    #pragma unroll
    for (int q = 0; q < 8; ++q) {
        float4 v = p[q];
        ea[q * 4] = v.x; ea[q * 4 + 1] = v.y; ea[q * 4 + 2] = v.z; ea[q * 4 + 3] = v.w;
    }
    for (int li = 0; li < LAYERS; ++li) {
        float out[8];
        #pragma unroll
        for (int h = 0; h < 8; ++h) {
            if (deg > 0) {
                const float* wr = &swe[(li * HEADS + h) * EDGE_F];
                float s = sbe[li * HEADS + h];
                #pragma unroll
                for (int c = 0; c < 32; ++c) s += ea[c] * wr[c];
                out[h] = s;
            } else out[h] = 0.f;
        }
        float4* dstp = (float4*)(preL + ((size_t)li * NN + n) * 8);
        dstp[0] = make_float4(out[0], out[1], out[2], out[3]);
        dstp[1] = make_float4(out[4], out[5], out[6], out[7]);
    }
}

// ---------------------------------------------------------------- bf16 hi/lo split
__device__ __forceinline__ ushort f2bf(float f) {
    union { float f; unsigned u; } v; v.f = f;
    unsigned u = v.u;
    return (ushort)((u + 0x7fffu + ((u >> 16) & 1u)) >> 16);
}
__device__ __forceinline__ float bf2f(ushort b) {
    union { unsigned u; float f; } v; v.u = ((unsigned)b) << 16; return v.f;
}

__global__ void split_kernel(const float* __restrict__ src, ushort* __restrict__ hi,
                             ushort* __restrict__ lo, int n) {
    int i = blockIdx.x * 256 + threadIdx.x;
    if (i >= n) return;
    float f = src[i];
    ushort h = f2bf(f);
    hi[i] = h;
    lo[i] = f2bf(f - bf2f(h));
}

// ---------------------------------------------------------------- bf16x3 MFMA GEMM (pre-split inputs)
__global__ __launch_bounds__(256) void gemm_bf3(const ushort* __restrict__ Ah,
                                                const ushort* __restrict__ Al,
                                                const ushort* __restrict__ Bh,
                                                const ushort* __restrict__ Bl,
                                                const float* __restrict__ bias,
                                                float* __restrict__ C,
                                                ushort* __restrict__ Chi, ushort* __restrict__ Clo,
                                                int N, int K, int J) {
    __shared__ ushort sAh[64][40], sAl[64][40], sBh[64][40], sBl[64][40];
    int nb = blockIdx.y * 64, jb = blockIdx.x * 64;
    int t = threadIdx.x, w = t >> 6, l = t & 63;
    int srow = t >> 2, sq = (t & 3) * 8;
    int fr = l & 15, fq = (l >> 4) * 8;
    float4v acc[4] = {};
    for (int kt = 0; kt < K; kt += 32) {
        int gr = nb + srow;
        short8 va = {0, 0, 0, 0, 0, 0, 0, 0}, vla = {0, 0, 0, 0, 0, 0, 0, 0};
        if (gr < N) {
            va = *(const short8*)(Ah + (size_t)gr * K + kt + sq);
            vla = *(const short8*)(Al + (size_t)gr * K + kt + sq);
        }
        *(short8*)&sAh[srow][sq] = va;
        *(short8*)&sAl[srow][sq] = vla;
        short8 vb = *(const short8*)(Bh + (size_t)(jb + srow) * K + kt + sq);
        short8 vlb = *(const short8*)(Bl + (size_t)(jb + srow) * K + kt + sq);
        *(short8*)&sBh[srow][sq] = vb;
        *(short8*)&sBl[srow][sq] = vlb;
        __syncthreads();
        short8 bh = *(const short8*)&sBh[w * 16 + fr][fq];
        short8 bl = *(const short8*)&sBl[w * 16 + fr][fq];
        #pragma unroll
        for (int mt = 0; mt < 4; ++mt) {
            short8 ah = *(const short8*)&sAh[mt * 16 + fr][fq];
            short8 al8 = *(const short8*)&sAl[mt * 16 + fr][fq];
            acc[mt] = __builtin_amdgcn_mfma_f32_16x16x32_bf16(ah, bh, acc[mt], 0, 0, 0);
            acc[mt] = __builtin_amdgcn_mfma_f32_16x16x32_bf16(ah, bl, acc[mt], 0, 0, 0);
            acc[mt] = __builtin_amdgcn_mfma_f32_16x16x32_bf16(al8, bh, acc[mt], 0, 0, 0);
        }
        __syncthreads();
    }
    int col = jb + w * 16 + fr;
    float bv = bias ? bias[col] : 0.f;
    #pragma unroll
    for (int mt = 0; mt < 4; ++mt) {
        #pragma unroll
        for (int r = 0; r < 4; ++r) {
            int row = nb + mt * 16 + (l >> 4) * 4 + r;
            if (row < N) {
                float v = acc[mt][r] + bv;
                C[(size_t)row * J + col] = v;
                if (Chi) {
                    ushort hh = f2bf(v);
                    Chi[(size_t)row * J + col] = hh;
                    Clo[(size_t)row * J + col] = f2bf(v - bf2f(hh));
                }
            }
        }
    }
}

// ---------------------------------------------------------------- per-node a_src/a_dst from xw
__global__ void asrcdst_kernel(const float* __restrict__ xw, const float* __restrict__ att_s,
                               const float* __restrict__ att_d, float* __restrict__ a_src,
                               float* __restrict__ a_dst) {
    int tid = blockIdx.x * 256 + threadIdx.x;
    if (tid >= NN * HEADS) return;
    int n = tid >> 3, h = tid & 7;
    const float4* xv = (const float4*)(xw + (size_t)n * HDIM + h * 32);
    const float4* sv = (const float4*)(att_s + h * 32);
    const float4* dv = (const float4*)(att_d + h * 32);
    float s1 = 0.f, s2 = 0.f;
    #pragma unroll
    for (int q = 0; q < 8; ++q) {
        float4 xx = xv[q], aa = sv[q], bb = dv[q];
        s1 += xx.x * aa.x + xx.y * aa.y + xx.z * aa.z + xx.w * aa.w;
        s2 += xx.x * bb.x + xx.y * bb.y + xx.z * bb.z + xx.w * bb.w;
    }
    a_src[tid] = s1;
    a_dst[tid] = s2;
}

__device__ __forceinline__ float gelu_exact(float x) {
    return 0.5f * x * (1.f + erff(x * 0.70710678118654752f));
}

// ---------------------------------------------------------------- fused alpha + softmax + aggregate + LN + GELU + residual
__global__ __launch_bounds__(64) void node_kernel(const float* __restrict__ xw,
                                                  const float* __restrict__ preE,
                                                  const float* __restrict__ preL,
                                                  const float* __restrict__ a_src,
                                                  const float* __restrict__ a_dst,
                                                  const int* __restrict__ row_ptr,
                                                  const int* __restrict__ csr_src,
                                                  const float* __restrict__ h_prev,
                                                  float* __restrict__ h_next,
                                                  ushort* __restrict__ hhi,
                                                  ushort* __restrict__ hlo,
                                                  const float* __restrict__ cb,
                                                  const float* __restrict__ lg,
                                                  const float* __restrict__ lb, int first) {
    __shared__ float lw[DCAP][9];  // stride 9 floats: odd → conflict-light scalar stores
    int n = blockIdx.x, l = threadIdx.x;
    int start = row_ptr[n], end = row_ptr[n + 1];

    float adn[8], alL[8], m[8];
    #pragma unroll
    for (int h = 0; h < 8; ++h) adn[h] = a_dst[n * 8 + h];
    #pragma unroll
    for (int h = 0; h < 8; ++h) {
        float al = a_src[n * 8 + h] + adn[h] + preL[n * 8 + h];
        alL[h] = al > 0.f ? al : 0.2f * al;
        m[h] = alL[h];
    }
    // pass 1: compute logits, cache in LDS, track max
    for (int idx = start + l; idx < end; idx += 64) {
        int sn = csr_src[idx];
        float4 p0 = *(const float4*)(preE + (size_t)idx * 8);
        float4 p1 = *(const float4*)(preE + (size_t)idx * 8 + 4);
        float4 s0 = *(const float4*)(a_src + (size_t)sn * 8);
        float4 s1 = *(const float4*)(a_src + (size_t)sn * 8 + 4);
        float al[8] = {s0.x + adn[0] + p0.x, s0.y + adn[1] + p0.y,
                       s0.z + adn[2] + p0.z, s0.w + adn[3] + p0.w,
                       s1.x + adn[4] + p1.x, s1.y + adn[5] + p1.y,
                       s1.z + adn[6] + p1.z, s1.w + adn[7] + p1.w};
        int o = idx - start;
        #pragma unroll
        for (int h = 0; h < 8; ++h) {
            al[h] = al[h] > 0.f ? al[h] : 0.2f * al[h];
            if (o < DCAP) lw[o][h] = al[h];
            m[h] = fmaxf(m[h], al[h]);
        }
    }
    #pragma unroll
    for (int off = 32; off >= 1; off >>= 1)
        #pragma unroll
        for (int h = 0; h < 8; ++h) m[h] = fmaxf(m[h], __shfl_xor(m[h], off, 64));

    float wl[8], s[8];
    #pragma unroll
    for (int h = 0; h < 8; ++h) {
        wl[h] = expf(alL[h] - m[h]);
        s[h] = (l == 0) ? wl[h] : 0.f;
    }
    // pass 2: exp + denom
    for (int idx = start + l; idx < end; idx += 64) {
        int o = idx - start;
        if (o < DCAP) {
            #pragma unroll
            for (int h = 0; h < 8; ++h) {
                float w = expf(lw[o][h] - m[h]);
                lw[o][h] = w;
                s[h] += w;
            }
        } else {  // rare fallback: recompute
            int sn = csr_src[idx];
            float4 p0 = *(const float4*)(preE + (size_t)idx * 8);
            float4 p1 = *(const float4*)(preE + (size_t)idx * 8 + 4);
            float4 s0 = *(const float4*)(a_src + (size_t)sn * 8);
            float4 s1 = *(const float4*)(a_src + (size_t)sn * 8 + 4);
            float al[8] = {s0.x + adn[0] + p0.x, s0.y + adn[1] + p0.y,
                           s0.z + adn[2] + p0.z, s0.w + adn[3] + p0.w,
                           s1.x + adn[4] + p1.x, s1.y + adn[5] + p1.y,
                           s1.z + adn[6] + p1.z, s1.w + adn[7] + p1.w};
            #pragma unroll
            for (int h = 0; h < 8; ++h) {
                al[h] = al[h] > 0.f ? al[h] : 0.2f * al[h];
                s[h] += expf(al[h] - m[h]);
            }
        }
    }
    #pragma unroll
    for (int off = 32; off >= 1; off >>= 1)
        #pragma unroll
        for (int h = 0; h < 8; ++h) s[h] += __shfl_xor(s[h], off, 64);
    float inv[8];
    #pragma unroll
    for (int h = 0; h < 8; ++h) inv[h] = 1.f / (s[h] + 1e-16f);
    __syncthreads();  // lw visible to all lanes

    // pass 3: weighted aggregate; lane owns channels l + 64j
    int h0 = l >> 5;  // head for j: h0 + 2j
    float acc[4];
    #pragma unroll
    for (int j = 0; j < 4; ++j) acc[j] = wl[h0 + 2 * j] * xw[(size_t)n * HDIM + l + 64 * j];
    for (int idx = start; idx < end; ++idx) {
        int sn = csr_src[idx];
        const float* xr = xw + (size_t)sn * HDIM;
        int o = idx - start;
        float wt[4];
        if (o < DCAP) {
            #pragma unroll
            for (int j = 0; j < 4; ++j) wt[j] = lw[o][h0 + 2 * j];
        } else {  // rare fallback
            float4 p0 = *(const float4*)(preE + (size_t)idx * 8);
            float4 p1 = *(const float4*)(preE + (size_t)idx * 8 + 4);
            float4 s0 = *(const float4*)(a_src + (size_t)sn * 8);
            float4 s1 = *(const float4*)(a_src + (size_t)sn * 8 + 4);
            float al[8] = {s0.x + adn[0] + p0.x, s0.y + adn[1] + p0.y,
                           s0.z + adn[2] + p0.z, s0.w + adn[3] + p0.w,
                           s1.x + adn[4] + p1.x, s1.y + adn[5] + p1.y,
                           s1.z + adn[6] + p1.z, s1.w + adn[7] + p1.w};
            #pragma unroll
            for (int j = 0; j < 4; ++j) {
                int h = h0 + 2 * j;
                float a = al[h] > 0.f ? al[h] : 0.2f * al[h];
                wt[j] = expf(a - m[h]);
            }
        }
        #pragma unroll
        for (int j = 0; j < 4; ++j) acc[j] += wt[j] * xr[l + 64 * j];
    }
    #pragma unroll
    for (int j = 0; j < 4; ++j) {
        int ch = l + 64 * j;
        acc[j] = acc[j] * inv[h0 + 2 * j] + cb[ch];
    }

    // LayerNorm over 256 channels
    float part = acc[0] + acc[1] + acc[2] + acc[3];
    #pragma unroll
    for (int off = 32; off >= 1; off >>= 1) part += __shfl_xor(part, off, 64);
    float mu = part * (1.f / 256.f);
    float p2 = 0.f;
    #pragma unroll
    for (int j = 0; j < 4; ++j) {
        float d = acc[j] - mu;
        p2 += d * d;
    }
    #pragma unroll
    for (int off = 32; off >= 1; off >>= 1) p2 += __shfl_xor(p2, off, 64);
    float rstd = rsqrtf(p2 * (1.f / 256.f) + 1e-5f);
    #pragma unroll
    for (int j = 0; j < 4; ++j) {
        int ch = l + 64 * j;
        float y = (acc[j] - mu) * rstd * lg[ch] + lb[ch];
        float g = gelu_exact(y);
        float o = g + (first ? 0.f : h_prev[(size_t)n * HDIM + ch]);
        h_next[(size_t)n * HDIM + ch] = o;
        ushort hh = f2bf(o);
        hhi[(size_t)n * HDIM + ch] = hh;
        hlo[(size_t)n * HDIM + ch] = f2bf(o - bf2f(hh));
    }
}

// ---------------------------------------------------------------- graph readout
__global__ __launch_bounds__(256) void graph_sum_kernel(const float* __restrict__ h,
                                                        const int* __restrict__ batch,
                                                        float* __restrict__ sums) {
    int t = threadIdx.x;
    int n0 = blockIdx.x * 64;
    int n1 = min(NN, n0 + 64);
    float acc = 0.f;
    int cur = batch[n0];
    for (int n = n0; n < n1; ++n) {
        int b = batch[n];
        if (b != cur) {
            atomicAdd(&sums[cur * HDIM + t], acc);
            acc = 0.f;
            cur = b;
        }
        acc += h[(size_t)n * HDIM + t];
    }
    atomicAdd(&sums[cur * HDIM + t], acc);
}

__device__ __forceinline__ int lower_bound_dev(const int* a, int n, int v) {
    int lo = 0, hi = n;
    while (lo < hi) {
        int mid = (lo + hi) >> 1;
        if (a[mid] < v) lo = mid + 1; else hi = mid;
    }
    return lo;
}

__global__ __launch_bounds__(256) void readout_mlp_kernel(
    const float* __restrict__ sums, const int* __restrict__ batch,
    const float* __restrict__ pw1, const float* __restrict__ pb1,
    const float* __restrict__ pw2, const float* __restrict__ pb2,
    const float* __restrict__ pw3, const float* __restrict__ pb3,
    const float* __restrict__ mw1, const float* __restrict__ mb1,
    const float* __restrict__ mw2, const float* __restrict__ mb2,
    const float* __restrict__ mw3, const float* __restrict__ mb3,
    float* __restrict__ out) {
    int g = blockIdx.x, t = threadIdx.x;
    __shared__ int se[2];
    __shared__ float xg[512];
    __shared__ float h1[256];
    __shared__ float h2[128];
    if (t == 0) {
        se[0] = lower_bound_dev(batch, NN, g);
        se[1] = lower_bound_dev(batch, NN, g + 1);
    }
    __syncthreads();
    float c = (float)(se[1] - se[0]);
    float s = sums[g * HDIM + t];
    xg[t] = s / fmaxf(c, 1.f);
    xg[256 + t] = s;
    __syncthreads();

    for (int which = 0; which < 2; ++which) {
        const float* w1 = which ? mw1 : pw1; const float* b1 = which ? mb1 : pb1;
        const float* w2 = which ? mw2 : pw2; const float* b2 = which ? mb2 : pb2;
        const float* w3 = which ? mw3 : pw3; const float* b3 = which ? mb3 : pb3;
        {
            const float4* wr = (const float4*)(w1 + (size_t)t * 512);
            const float4* xv = (const float4*)xg;
            float s1 = 0.f;
            for (int k = 0; k < 128; ++k) {
                float4 w = wr[k], x = xv[k];
                s1 += w.x * x.x + w.y * x.y + w.z * x.z + w.w * x.w;
            }
            h1[t] = gelu_exact(s1 + b1[t]);
        }
        __syncthreads();
        if (t < 128) {
            const float4* wr = (const float4*)(w2 + (size_t)t * 256);
            const float4* xv = (const float4*)h1;
            float s1 = 0.f;
            for (int k = 0; k < 64; ++k) {
                float4 w = wr[k], x = xv[k];
                s1 += w.x * x.x + w.y * x.y + w.z * x.z + w.w * x.w;
            }
            h2[t] = gelu_exact(s1 + b2[t]);
        }
        __syncthreads();
        if (t < 3) {
            const float* wr = w3 + t * 128;
            float s1 = 0.f;
            for (int k = 0; k < 128; ++k) s1 += wr[k] * h2[k];
            s1 += b3[t];
            out[which * (NG * 3) + g * 3 + t] = 1.f / (1.f + expf(-s1));
        }
        __syncthreads();
    }
}

// ---------------------------------------------------------------- launch
extern "C" void kernel_launch(void* const* d_in, const int* in_sizes, int n_in, void* d_out,
                              int out_size, void* d_ws, size_t ws_size, hipStream_t stream) {
    const float* x         = (const float*)d_in[0];
    const int*   ei        = (const int*)d_in[1];
    const int*   src       = ei;
    const int*   dst       = ei + NE;
    const float* edge_attr = (const float*)d_in[2];
    const int*   batch     = (const int*)d_in[3];
    const float* node_w    = (const float*)d_in[4];
    const float* node_b    = (const float*)d_in[5];
    const float* eew       = (const float*)d_in[6];
    const float* eeb       = (const float*)d_in[7];
    const float* lin_w     = (const float*)d_in[8];
    const float* att_src   = (const float*)d_in[9];
    const float* att_dst   = (const float*)d_in[10];
    const float* att_edge  = (const float*)d_in[11];
    const float* lin_edge_w= (const float*)d_in[12];
    const float* conv_b    = (const float*)d_in[13];
    const float* ln_g      = (const float*)d_in[14];
    const float* ln_b      = (const float*)d_in[15];
    const float* pw1 = (const float*)d_in[16]; const float* pb1 = (const float*)d_in[17];
    const float* pw2 = (const float*)d_in[18]; const float* pb2 = (const float*)d_in[19];
    const float* pw3 = (const float*)d_in[20]; const float* pb3 = (const float*)d_in[21];
    const float* mw1 = (const float*)d_in[22]; const float* mb1 = (const float*)d_in[23];
    const float* mw2 = (const float*)d_in[24]; const float* mb2 = (const float*)d_in[25];
    const float* mw3 = (const float*)d_in[26]; const float* mb3 = (const float*)d_in[27];
    float* out = (float*)d_out;

    float* wsf = (float*)d_ws;
    float* hA        = wsf; wsf += (size_t)NN * HDIM;
    float* hB        = wsf; wsf += (size_t)NN * HDIM;
    float* xw        = wsf; wsf += (size_t)NN * HDIM;
    float* preE      = wsf; wsf += (size_t)LAYERS * NE * 8;
    float* preL      = wsf; wsf += (size_t)LAYERS * NN * 8;
    float* a_src     = wsf; wsf += (size_t)NN * HEADS;
    float* a_dst     = wsf; wsf += (size_t)NN * HEADS;
    float* mean_attr = wsf; wsf += (size_t)NN * EDGE_F;
    float* vbuf      = wsf; wsf += (size_t)LAYERS * HEADS * HDIM;
    float* webuf     = wsf; wsf += (size_t)LAYERS * HEADS * EDGE_F;
    float* bebuf     = wsf; wsf += 64;
    float* sums      = wsf; wsf += (size_t)NG * HDIM;
    ushort* ubuf = (ushort*)wsf;
    ushort* hhi  = ubuf; ubuf += (size_t)NN * HDIM;
    ushort* hlo  = ubuf; ubuf += (size_t)NN * HDIM;
    ushort* wbhi = ubuf; ubuf += (size_t)LAYERS * HDIM * HDIM;
    ushort* wblo = ubuf; ubuf += (size_t)LAYERS * HDIM * HDIM;
    ushort* xhi  = ubuf; ubuf += (size_t)NN * NODE_F;
    ushort* xlo  = ubuf; ubuf += (size_t)NN * NODE_F;
    ushort* nwhi = ubuf; ubuf += (size_t)HDIM * NODE_F;
    ushort* nwlo = ubuf; ubuf += (size_t)HDIM * NODE_F;
    int* ibuf    = (int*)ubuf;
    int* cnt     = ibuf; ibuf += NN + 16;
    int* row_ptr = ibuf; ibuf += NN + 16;
    int* pos     = ibuf; ibuf += NN + 16;
    int* csr_src = ibuf; ibuf += NE;
    int* csr_eid = ibuf; ibuf += NE;

    // CSR build
    hipMemsetAsync(cnt, 0, NN * sizeof(int), stream);
    count_kernel<<<(NE + 255) / 256, 256, 0, stream>>>(dst, cnt);
    scan_kernel<<<1, 1024, 0, stream>>>(cnt, row_ptr, pos);
    scatter_kernel<<<(NE + 255) / 256, 256, 0, stream>>>(src, dst, pos, csr_src, csr_eid);
    mean_attr_kernel<<<NN, 64, 0, stream>>>(edge_attr, row_ptr, csr_eid, mean_attr);

    // fold edge-attention weights, then hoist layer-invariant logit partials
    v_kernel<<<(LAYERS * HEADS * HDIM + 255) / 256, 256, 0, stream>>>(att_edge, lin_edge_w, vbuf);
    we_kernel<<<(LAYERS * HEADS * EDGE_F + LAYERS * HEADS + 255) / 256, 256, 0, stream>>>(
        vbuf, eew, eeb, webuf, bebuf);
    preE_kernel<<<(NE + 255) / 256, 256, 0, stream>>>(csr_eid, edge_attr, webuf, bebuf, preE);
    preL_kernel<<<(NN + 255) / 256, 256, 0, stream>>>(mean_attr, row_ptr, webuf, bebuf, preL);

    // pre-split GEMM operands to bf16 hi/lo
    split_kernel<<<((LAYERS * HDIM * HDIM) + 255) / 256, 256, 0, stream>>>(lin_w, wbhi, wblo,
                                                                           LAYERS * HDIM * HDIM);
    split_kernel<<<((NN * NODE_F) + 255) / 256, 256, 0, stream>>>(x, xhi, xlo, NN * NODE_F);
    split_kernel<<<((HDIM * NODE_F) + 255) / 256, 256, 0, stream>>>(node_w, nwhi, nwlo,
                                                                    HDIM * NODE_F);

    // node embedding: hA = x @ node_w.T + node_b  (+ bf16 split of hA)
    {
        dim3 grid(HDIM / 64, (NN + 63) / 64);
        gemm_bf3<<<grid, 256, 0, stream>>>(xhi, xlo, nwhi, nwlo, node_b, hA, hhi, hlo,
                                           NN, NODE_F, HDIM);
    }

    float* cur = hA;
    float* nxt = hB;
    for (int i = 0; i < LAYERS; ++i) {
        dim3 grid(HDIM / 64, (NN + 63) / 64);
        gemm_bf3<<<grid, 256, 0, stream>>>(hhi, hlo, wbhi + (size_t)i * HDIM * HDIM,
                                           wblo + (size_t)i * HDIM * HDIM, nullptr, xw,
                                           nullptr, nullptr, NN, HDIM, HDIM);
        asrcdst_kernel<<<(NN * HEADS + 255) / 256, 256, 0, stream>>>(
            xw, att_src + i * HEADS * 32, att_dst + i * HEADS * 32, a_src, a_dst);
        node_kernel<<<NN, 64, 0, stream>>>(xw, preE + (size_t)i * NE * 8,
                                           preL + (size_t)i * NN * 8, a_src, a_dst, row_ptr,
                                           csr_src, cur, nxt, hhi, hlo, conv_b + i * HDIM,
                                           ln_g + i * HDIM, ln_b + i * HDIM, i == 0 ? 1 : 0);
        float* tmp = cur; cur = nxt; nxt = tmp;
    }

    hipMemsetAsync(sums, 0, NG * HDIM * sizeof(float), stream);
    graph_sum_kernel<<<(NN + 63) / 64, 256, 0, stream>>>(cur, batch, sums);
    readout_mlp_kernel<<<NG, 256, 0, stream>>>(sums, batch, pw1, pb1, pw2, pb2, pw3, pb3, mw1,
                                               mb1, mw2, mb2, mw3, mb3, out);
}